// Round 12
// baseline (248.602 us; speedup 1.0000x reference)
//
#include <hip/hip_runtime.h>
#include <hip/hip_bf16.h>
#include <cstdint>
#include <cstddef>

// SupConLoss, N=16384 D=128, T=0.07, 100 classes.
// Round 3: Round-2 pipelined triangular structure, but ATOMIC-FREE hot kernel.
// Round-2 PMC showed 2.6M device-scope atomicAdds -> 321 MB near-memory RMW
// traffic at 1.9 TB/s = the whole 170us. Replace with owner-writes-once
// float2 partial arrays (pCol[I][Jcol], pRow[c][Irow]) + fused reduce kernel
// that sums only the valid slots (no zero-init needed).

#define N_ROWS 16384
#define DIM    128
#define TILE   128
#define NTILES (N_ROWS / TILE)   // 128
#define NCHUNK 32                // J-chunks of 4 tiles

// exp(sim/T) = exp2( dot * log2(e)/T ); bake sqrt(log2(e)/T) into features.
#define FEAT_SCALE 4.5398164f

typedef __attribute__((ext_vector_type(8))) short bf16x8;
typedef __attribute__((ext_vector_type(4))) float f32x4;

typedef const __attribute__((address_space(1))) unsigned int* gas_ptr;
typedef __attribute__((address_space(3))) unsigned int* las_ptr;

// ---------------------------------------------------------------- normalize
__global__ __launch_bounds__(256) void k_normalize(const float* __restrict__ F,
                                                   __hip_bfloat16* __restrict__ G) {
    int tid  = threadIdx.x;
    int lane = tid & 63;
    int wave = tid >> 6;
    int row  = blockIdx.x * 4 + wave;
    const float2* src = (const float2*)(F + (size_t)row * DIM) + lane;
    float2 x = *src;
    float s = x.x * x.x + x.y * x.y;
#pragma unroll
    for (int i = 1; i < 64; i <<= 1) s += __shfl_xor(s, i, 64);
    float scale = FEAT_SCALE / fmaxf(sqrtf(s), 1e-12f);
    __hip_bfloat162 h;
    h.x = __float2bfloat16(x.x * scale);
    h.y = __float2bfloat16(x.y * scale);
    ((__hip_bfloat162*)(G + (size_t)row * DIM))[lane] = h;
}

// ---------------------------------------------------------------- main tiles
// Block = (I, chunk c): I-tile rows, J-tiles J0..J0+nj-1 (nj<=4, J>=I).
// ATOM=false: pRow = float2[NCHUNK][N_ROWS], pCol = float2[NTILES][N_ROWS],
//             each slot written exactly once (plain stores, no init needed).
// ATOM=true : pRow/pCol reinterpreted as float rN[N]/rT[N] atomics (fallback).
template<bool ATOM>
__global__ __launch_bounds__(256, 2) void k_tiles(const __hip_bfloat16* __restrict__ G,
                                                  const int* __restrict__ lab,
                                                  float2* __restrict__ pRow,
                                                  float2* __restrict__ pCol) {
    __shared__ __align__(16) char lds[65536 + 2048];
    float* sRed = (float*)(lds + 65536);   // 512 floats, reused col/row phases

    int tid = threadIdx.x;

    // ---- triangular decode: bid -> (I, chunk c) with c >= I/4
    int bid = blockIdx.x;
    int u = bid >> 2, i2 = bid & 3;
    int c = (int)((sqrtf(8.f * (float)u + 1.f) - 1.f) * 0.5f);
    while ((c + 1) * (c + 2) / 2 <= u) ++c;
    while (c * (c + 1) / 2 > u) --c;
    int g = u - c * (c + 1) / 2;          // g <= c
    int I = g * 4 + i2;
    int J0 = (I > c * 4) ? I : c * 4;
    int nj = c * 4 + 4 - J0;              // 1..4

    // ---- stage A -> lds[0,32K), B(J0) -> lds[32K,64K)  (pre-swizzled source)
    const char* gbase = (const char*)G;
    {
        const char* gA = gbase + (size_t)I * (TILE * DIM * 2);
        const char* gB = gbase + (size_t)J0 * (TILE * DIM * 2);
#pragma unroll
        for (int p = 0; p < 8; ++p) {
            int o = p * 4096 + tid * 16;
            int so = o ^ (((o >> 8) & 7) << 4);
            __builtin_amdgcn_global_load_lds((gas_ptr)(gA + so), (las_ptr)(lds + o), 16, 0, 0);
            __builtin_amdgcn_global_load_lds((gas_ptr)(gB + so), (las_ptr)(lds + 32768 + o), 16, 0, 0);
        }
    }

    int lane = tid & 63, w = tid >> 6;
    int wr = w >> 1, wc = w & 1;          // 2x2 waves of 64x64
    int lr = lane & 15, lhi = lane >> 4;

    __syncthreads();                      // drains vmcnt -> A,B0 resident

    // ---- A fragments to registers (64 VGPRs), row labels
    bf16x8 afr[4][4];                     // [m][kk]
#pragma unroll
    for (int m = 0; m < 4; ++m) {
        int row = wr * 64 + m * 16 + lr;
#pragma unroll
        for (int kk = 0; kk < 4; ++kk) {
            int lin = row * 256 + kk * 64 + lhi * 16;
            afr[m][kk] = *(const bf16x8*)(lds + (lin ^ ((row & 7) << 4)));
        }
    }
    int rowbase = I * TILE + wr * 64;
    int labr[4][4];
#pragma unroll
    for (int m = 0; m < 4; ++m)
#pragma unroll
        for (int r = 0; r < 4; ++r) labr[m][r] = lab[rowbase + m * 16 + lhi * 4 + r];

    float rn[4][4], rt[4][4];
#pragma unroll
    for (int m = 0; m < 4; ++m)
#pragma unroll
        for (int r = 0; r < 4; ++r) { rn[m][r] = 0.f; rt[m][r] = 0.f; }

    __syncthreads();                      // all waves done reading A region

    // ---- J loop, double-buffered B
    for (int t = 0; t < nj; ++t) {
        char* buf = lds + (((t & 1) ^ 1) << 15);   // B(t)
        int Jt = J0 + t;

        if (t + 1 < nj) {                 // issue B(t+1) early -> hidden
            const char* gB = gbase + (size_t)(Jt + 1) * (TILE * DIM * 2);
            char* nbuf = lds + ((t & 1) << 15);
#pragma unroll
            for (int p = 0; p < 8; ++p) {
                int o = p * 4096 + tid * 16;
                int so = o ^ (((o >> 8) & 7) << 4);
                __builtin_amdgcn_global_load_lds((gas_ptr)(gB + so), (las_ptr)(nbuf + o), 16, 0, 0);
            }
        }
        __builtin_amdgcn_sched_barrier(0);  // keep stage issue ahead of compute

        int colbase = Jt * TILE + wc * 64;
        int labc[4];
#pragma unroll
        for (int n = 0; n < 4; ++n) labc[n] = lab[colbase + n * 16 + lr];

        f32x4 acc[4][4];
#pragma unroll
        for (int m = 0; m < 4; ++m)
#pragma unroll
            for (int n = 0; n < 4; ++n) acc[m][n] = (f32x4){0.f, 0.f, 0.f, 0.f};

#pragma unroll
        for (int kk = 0; kk < 4; ++kk) {
            bf16x8 b[4];
#pragma unroll
            for (int n = 0; n < 4; ++n) {
                int row = wc * 64 + n * 16 + lr;
                int lin = row * 256 + kk * 64 + lhi * 16;
                b[n] = *(const bf16x8*)(buf + (lin ^ ((row & 7) << 4)));
            }
#pragma unroll
            for (int m = 0; m < 4; ++m)
#pragma unroll
                for (int n = 0; n < 4; ++n)
                    acc[m][n] = __builtin_amdgcn_mfma_f32_16x16x32_bf16(afr[m][kk], b[n], acc[m][n], 0, 0, 0);
        }

        // ---- fused epilogue
        float cn[4] = {0.f, 0.f, 0.f, 0.f}, ct[4] = {0.f, 0.f, 0.f, 0.f};
        bool isdiag = (Jt == I);
        if (isdiag) {
#pragma unroll
            for (int n = 0; n < 4; ++n) {
                int col = colbase + n * 16 + lr;
#pragma unroll
                for (int m = 0; m < 4; ++m) {
                    int row0 = rowbase + m * 16 + lhi * 4;
#pragma unroll
                    for (int r = 0; r < 4; ++r) {
                        float e = __builtin_amdgcn_exp2f(acc[m][n][r]);
                        float te = ((row0 + r) != col) ? e : 0.f;
                        float me = (labr[m][r] == labc[n]) ? te : 0.f;
                        rn[m][r] += me;  rt[m][r] += te;
                        cn[n]    += me;  ct[n]    += te;
                    }
                }
            }
        } else {
#pragma unroll
            for (int n = 0; n < 4; ++n) {
#pragma unroll
                for (int m = 0; m < 4; ++m) {
#pragma unroll
                    for (int r = 0; r < 4; ++r) {
                        float e = __builtin_amdgcn_exp2f(acc[m][n][r]);
                        float me = (labr[m][r] == labc[n]) ? e : 0.f;
                        rn[m][r] += me;  rt[m][r] += e;
                        cn[n]    += me;  ct[n]    += e;
                    }
                }
            }
        }

        // ---- col partials: reduce over lhi, combine 2 wr-waves, store once
#pragma unroll
        for (int n = 0; n < 4; ++n) {
            float v1 = cn[n], v2 = ct[n];
            v1 += __shfl_xor(v1, 16, 64); v1 += __shfl_xor(v1, 32, 64);
            v2 += __shfl_xor(v2, 16, 64); v2 += __shfl_xor(v2, 32, 64);
            if (lhi == 0) {
                int colt = wc * 64 + n * 16 + lr;
                sRed[wr * 128 + colt]       = v1;
                sRed[256 + wr * 128 + colt] = v2;
            }
        }
        __syncthreads();                  // also drains B(t+1) staging
        if (!isdiag && tid < 128) {
            float2 v;
            v.x = sRed[tid] + sRed[128 + tid];
            v.y = sRed[256 + tid] + sRed[384 + tid];
            if (ATOM) {
                float* rN = (float*)pRow;  float* rT = (float*)pCol;
                atomicAdd(&rN[Jt * TILE + tid], v.x);
                atomicAdd(&rT[Jt * TILE + tid], v.y);
            } else {
                pCol[(size_t)I * N_ROWS + Jt * TILE + tid] = v;   // owner-unique slot
            }
        }
        __syncthreads();                  // sRed free for next tile
    }

    // ---- row partials: reduce over lr once per block, store once
#pragma unroll
    for (int m = 0; m < 4; ++m)
#pragma unroll
        for (int r = 0; r < 4; ++r) {
            float v1 = rn[m][r], v2 = rt[m][r];
#pragma unroll
            for (int s = 1; s < 16; s <<= 1) {
                v1 += __shfl_xor(v1, s, 64);
                v2 += __shfl_xor(v2, s, 64);
            }
            if (lr == 0) {
                int rowt = wr * 64 + m * 16 + lhi * 4 + r;
                sRed[wc * 128 + rowt]       = v1;
                sRed[256 + wc * 128 + rowt] = v2;
            }
        }
    __syncthreads();
    if (tid < 128) {
        float2 v;
        v.x = sRed[tid] + sRed[128 + tid];
        v.y = sRed[256 + tid] + sRed[384 + tid];
        if (ATOM) {
            float* rN = (float*)pRow;  float* rT = (float*)pCol;
            atomicAdd(&rN[I * TILE + tid], v.x);
            atomicAdd(&rT[I * TILE + tid], v.y);
        } else {
            pRow[(size_t)c * N_ROWS + I * TILE + tid] = v;        // owner-unique slot
        }
    }
}

// ---------------------------------------------------------------- reduce+loss+mean
// Valid slots: row r (tile it=r>>7): pRow[c][r] for c=it/4..31; pCol[I][r] for I=0..it-1.
template<bool ATOM>
__global__ __launch_bounds__(256) void k_reduce(const float2* __restrict__ pRow,
                                                const float2* __restrict__ pCol,
                                                float* __restrict__ accum) {
    int row = blockIdx.x * 256 + threadIdx.x;
    float num = 0.f, tot = 0.f;
    if (ATOM) {
        num = ((const float*)pRow)[row];
        tot = ((const float*)pCol)[row];
    } else {
        int it = row >> 7;
        for (int c = it >> 2; c < NCHUNK; ++c) {
            float2 v = pRow[(size_t)c * N_ROWS + row];
            num += v.x; tot += v.y;
        }
        for (int I = 0; I < it; ++I) {
            float2 v = pCol[(size_t)I * N_ROWS + row];
            num += v.x; tot += v.y;
        }
    }
    float ediag = expf(14.285714285714286f);       // exp(1/T), exact diagonal
    float denom = tot - num + ediag;
    float loss = -logf(num / denom + 1e-8f);
#pragma unroll
    for (int i = 1; i < 64; i <<= 1) loss += __shfl_xor(loss, i, 64);
    __shared__ float red[4];
    if ((threadIdx.x & 63) == 0) red[threadIdx.x >> 6] = loss;
    __syncthreads();
    if (threadIdx.x == 0)
        atomicAdd(accum, red[0] + red[1] + red[2] + red[3]);
}

__global__ void k_final(const float* __restrict__ accum, float* __restrict__ out) {
    out[0] = accum[0] / (float)N_ROWS;
}

// ---------------------------------------------------------------- launcher
extern "C" void kernel_launch(void* const* d_in, const int* in_sizes, int n_in,
                              void* d_out, int out_size, void* d_ws, size_t ws_size,
                              hipStream_t stream) {
    const float* F  = (const float*)d_in[0];
    const int* lab  = (const int*)d_in[1];
    float* out      = (float*)d_out;
    char* ws        = (char*)d_ws;

    __hip_bfloat16* G = (__hip_bfloat16*)ws;                         // 4 MB
    float* accum = (float*)(ws + ((size_t)4 << 20));                 // 16 B
    char* base   = ws + ((size_t)4 << 20) + 1024;
    float2* pRow = (float2*)base;                                    // 4 MB  [32][16384]
    float2* pCol = (float2*)(base + ((size_t)4 << 20));              // 16 MB [128][16384]

    k_normalize<<<N_ROWS / 4, 256, 0, stream>>>(F, G);
    hipMemsetAsync(accum, 0, 16, stream);

    size_t need = ((size_t)4 << 20) + 1024 + ((size_t)4 << 20) + ((size_t)16 << 20);
    int nblocks = 2112;   // sum over I-tiles of #4-wide J-chunks (triangle)
    if (ws_size >= need) {
        k_tiles<false><<<nblocks, 256, 0, stream>>>(G, lab, pRow, pCol);
        k_reduce<false><<<N_ROWS / 256, 256, 0, stream>>>(pRow, pCol, accum);
    } else {
        // fallback: pRow/pCol reused as rN[N]/rT[N] float accumulators
        hipMemsetAsync(pRow, 0, (size_t)N_ROWS * sizeof(float), stream);
        hipMemsetAsync(pCol, 0, (size_t)N_ROWS * sizeof(float), stream);
        k_tiles<true><<<nblocks, 256, 0, stream>>>(G, lab, pRow, pCol);
        k_reduce<true><<<N_ROWS / 256, 256, 0, stream>>>(pRow, pCol, accum);
    }
    k_final<<<1, 1, 0, stream>>>(accum, out);
}

// Round 13
// 234.656 us; speedup vs baseline: 1.0594x; 1.0594x over previous
//
#include <hip/hip_runtime.h>
#include <hip/hip_bf16.h>
#include <cstdint>
#include <cstddef>

// SupConLoss, N=16384 D=128, T=0.07, 100 classes.
// Round 4: Round-3 structure, SPILL FIX. Round-3 PMC showed 105 KB/block of
// scratch writes (WRITE_SIZE 223 MB unchanged after atomic removal): the
// VGPR allocator capped at 128 under __launch_bounds__(256,2) and spilled
// the ~200-reg working set (afr 64 + acc 64 + ...). Fix: drop the min-waves
// arg (LDS 66K already caps occupancy at 2 blocks/CU -> 256-VGPR budget) and
// shorten B-fragment live ranges in the MFMA loop.

#define N_ROWS 16384
#define DIM    128
#define TILE   128
#define NTILES (N_ROWS / TILE)   // 128
#define NCHUNK 32                // J-chunks of 4 tiles

// exp(sim/T) = exp2( dot * log2(e)/T ); bake sqrt(log2(e)/T) into features.
#define FEAT_SCALE 4.5398164f

typedef __attribute__((ext_vector_type(8))) short bf16x8;
typedef __attribute__((ext_vector_type(4))) float f32x4;

typedef const __attribute__((address_space(1))) unsigned int* gas_ptr;
typedef __attribute__((address_space(3))) unsigned int* las_ptr;

// ---------------------------------------------------------------- normalize
__global__ __launch_bounds__(256) void k_normalize(const float* __restrict__ F,
                                                   __hip_bfloat16* __restrict__ G) {
    int tid  = threadIdx.x;
    int lane = tid & 63;
    int wave = tid >> 6;
    int row  = blockIdx.x * 4 + wave;
    const float2* src = (const float2*)(F + (size_t)row * DIM) + lane;
    float2 x = *src;
    float s = x.x * x.x + x.y * x.y;
#pragma unroll
    for (int i = 1; i < 64; i <<= 1) s += __shfl_xor(s, i, 64);
    float scale = FEAT_SCALE / fmaxf(sqrtf(s), 1e-12f);
    __hip_bfloat162 h;
    h.x = __float2bfloat16(x.x * scale);
    h.y = __float2bfloat16(x.y * scale);
    ((__hip_bfloat162*)(G + (size_t)row * DIM))[lane] = h;
}

// ---------------------------------------------------------------- main tiles
// Block = (I, chunk c): I-tile rows, J-tiles J0..J0+nj-1 (nj<=4, J>=I).
// ATOM=false: pRow = float2[NCHUNK][N_ROWS], pCol = float2[NTILES][N_ROWS],
//             each slot written exactly once (plain stores, no init needed).
// ATOM=true : pRow/pCol reinterpreted as float rN[N]/rT[N] atomics (fallback).
template<bool ATOM>
__global__ __launch_bounds__(256) void k_tiles(const __hip_bfloat16* __restrict__ G,
                                               const int* __restrict__ lab,
                                               float2* __restrict__ pRow,
                                               float2* __restrict__ pCol) {
    __shared__ __align__(16) char lds[65536 + 2048];
    float* sRed = (float*)(lds + 65536);   // 512 floats, reused col/row phases

    int tid = threadIdx.x;

    // ---- triangular decode: bid -> (I, chunk c) with c >= I/4
    int bid = blockIdx.x;
    int u = bid >> 2, i2 = bid & 3;
    int c = (int)((sqrtf(8.f * (float)u + 1.f) - 1.f) * 0.5f);
    while ((c + 1) * (c + 2) / 2 <= u) ++c;
    while (c * (c + 1) / 2 > u) --c;
    int g = u - c * (c + 1) / 2;          // g <= c
    int I = g * 4 + i2;
    int J0 = (I > c * 4) ? I : c * 4;
    int nj = c * 4 + 4 - J0;              // 1..4

    // ---- stage A -> lds[0,32K), B(J0) -> lds[32K,64K)  (pre-swizzled source)
    const char* gbase = (const char*)G;
    {
        const char* gA = gbase + (size_t)I * (TILE * DIM * 2);
        const char* gB = gbase + (size_t)J0 * (TILE * DIM * 2);
#pragma unroll
        for (int p = 0; p < 8; ++p) {
            int o = p * 4096 + tid * 16;
            int so = o ^ (((o >> 8) & 7) << 4);
            __builtin_amdgcn_global_load_lds((gas_ptr)(gA + so), (las_ptr)(lds + o), 16, 0, 0);
            __builtin_amdgcn_global_load_lds((gas_ptr)(gB + so), (las_ptr)(lds + 32768 + o), 16, 0, 0);
        }
    }

    int lane = tid & 63, w = tid >> 6;
    int wr = w >> 1, wc = w & 1;          // 2x2 waves of 64x64
    int lr = lane & 15, lhi = lane >> 4;

    __syncthreads();                      // drains vmcnt -> A,B0 resident

    // ---- A fragments to registers (64 VGPRs), row labels
    bf16x8 afr[4][4];                     // [m][kk]
#pragma unroll
    for (int m = 0; m < 4; ++m) {
        int row = wr * 64 + m * 16 + lr;
#pragma unroll
        for (int kk = 0; kk < 4; ++kk) {
            int lin = row * 256 + kk * 64 + lhi * 16;
            afr[m][kk] = *(const bf16x8*)(lds + (lin ^ ((row & 7) << 4)));
        }
    }
    int rowbase = I * TILE + wr * 64;
    int labr[4][4];
#pragma unroll
    for (int m = 0; m < 4; ++m)
#pragma unroll
        for (int r = 0; r < 4; ++r) labr[m][r] = lab[rowbase + m * 16 + lhi * 4 + r];

    float rn[4][4], rt[4][4];
#pragma unroll
    for (int m = 0; m < 4; ++m)
#pragma unroll
        for (int r = 0; r < 4; ++r) { rn[m][r] = 0.f; rt[m][r] = 0.f; }

    __syncthreads();                      // all waves done reading A region

    // ---- J loop, double-buffered B
    for (int t = 0; t < nj; ++t) {
        char* buf = lds + (((t & 1) ^ 1) << 15);   // B(t)
        int Jt = J0 + t;

        if (t + 1 < nj) {                 // issue B(t+1) early -> hidden
            const char* gB = gbase + (size_t)(Jt + 1) * (TILE * DIM * 2);
            char* nbuf = lds + ((t & 1) << 15);
#pragma unroll
            for (int p = 0; p < 8; ++p) {
                int o = p * 4096 + tid * 16;
                int so = o ^ (((o >> 8) & 7) << 4);
                __builtin_amdgcn_global_load_lds((gas_ptr)(gB + so), (las_ptr)(nbuf + o), 16, 0, 0);
            }
        }
        __builtin_amdgcn_sched_barrier(0);  // keep stage issue ahead of compute

        int colbase = Jt * TILE + wc * 64;
        int labc[4];
#pragma unroll
        for (int n = 0; n < 4; ++n) labc[n] = lab[colbase + n * 16 + lr];

        f32x4 acc[4][4];
#pragma unroll
        for (int m = 0; m < 4; ++m)
#pragma unroll
            for (int n = 0; n < 4; ++n) acc[m][n] = (f32x4){0.f, 0.f, 0.f, 0.f};

        // B fragment consumed immediately after load (1 live bf16x8, not 4)
#pragma unroll
        for (int kk = 0; kk < 4; ++kk) {
#pragma unroll
            for (int n = 0; n < 4; ++n) {
                int row = wc * 64 + n * 16 + lr;
                int lin = row * 256 + kk * 64 + lhi * 16;
                bf16x8 b = *(const bf16x8*)(buf + (lin ^ ((row & 7) << 4)));
#pragma unroll
                for (int m = 0; m < 4; ++m)
                    acc[m][n] = __builtin_amdgcn_mfma_f32_16x16x32_bf16(afr[m][kk], b, acc[m][n], 0, 0, 0);
            }
        }

        // ---- fused epilogue
        float cn[4] = {0.f, 0.f, 0.f, 0.f}, ct[4] = {0.f, 0.f, 0.f, 0.f};
        bool isdiag = (Jt == I);
        if (isdiag) {
#pragma unroll
            for (int n = 0; n < 4; ++n) {
                int col = colbase + n * 16 + lr;
#pragma unroll
                for (int m = 0; m < 4; ++m) {
                    int row0 = rowbase + m * 16 + lhi * 4;
#pragma unroll
                    for (int r = 0; r < 4; ++r) {
                        float e = __builtin_amdgcn_exp2f(acc[m][n][r]);
                        float te = ((row0 + r) != col) ? e : 0.f;
                        float me = (labr[m][r] == labc[n]) ? te : 0.f;
                        rn[m][r] += me;  rt[m][r] += te;
                        cn[n]    += me;  ct[n]    += te;
                    }
                }
            }
        } else {
#pragma unroll
            for (int n = 0; n < 4; ++n) {
#pragma unroll
                for (int m = 0; m < 4; ++m) {
#pragma unroll
                    for (int r = 0; r < 4; ++r) {
                        float e = __builtin_amdgcn_exp2f(acc[m][n][r]);
                        float me = (labr[m][r] == labc[n]) ? e : 0.f;
                        rn[m][r] += me;  rt[m][r] += e;
                        cn[n]    += me;  ct[n]    += e;
                    }
                }
            }
        }

        // ---- col partials: reduce over lhi, combine 2 wr-waves, store once
#pragma unroll
        for (int n = 0; n < 4; ++n) {
            float v1 = cn[n], v2 = ct[n];
            v1 += __shfl_xor(v1, 16, 64); v1 += __shfl_xor(v1, 32, 64);
            v2 += __shfl_xor(v2, 16, 64); v2 += __shfl_xor(v2, 32, 64);
            if (lhi == 0) {
                int colt = wc * 64 + n * 16 + lr;
                sRed[wr * 128 + colt]       = v1;
                sRed[256 + wr * 128 + colt] = v2;
            }
        }
        __syncthreads();                  // also drains B(t+1) staging
        if (!isdiag && tid < 128) {
            float2 v;
            v.x = sRed[tid] + sRed[128 + tid];
            v.y = sRed[256 + tid] + sRed[384 + tid];
            if (ATOM) {
                float* rN = (float*)pRow;  float* rT = (float*)pCol;
                atomicAdd(&rN[Jt * TILE + tid], v.x);
                atomicAdd(&rT[Jt * TILE + tid], v.y);
            } else {
                pCol[(size_t)I * N_ROWS + Jt * TILE + tid] = v;   // owner-unique slot
            }
        }
        __syncthreads();                  // sRed free for next tile
    }

    // ---- row partials: reduce over lr once per block, store once
#pragma unroll
    for (int m = 0; m < 4; ++m)
#pragma unroll
        for (int r = 0; r < 4; ++r) {
            float v1 = rn[m][r], v2 = rt[m][r];
#pragma unroll
            for (int s = 1; s < 16; s <<= 1) {
                v1 += __shfl_xor(v1, s, 64);
                v2 += __shfl_xor(v2, s, 64);
            }
            if (lr == 0) {
                int rowt = wr * 64 + m * 16 + lhi * 4 + r;
                sRed[wc * 128 + rowt]       = v1;
                sRed[256 + wc * 128 + rowt] = v2;
            }
        }
    __syncthreads();
    if (tid < 128) {
        float2 v;
        v.x = sRed[tid] + sRed[128 + tid];
        v.y = sRed[256 + tid] + sRed[384 + tid];
        if (ATOM) {
            float* rN = (float*)pRow;  float* rT = (float*)pCol;
            atomicAdd(&rN[I * TILE + tid], v.x);
            atomicAdd(&rT[I * TILE + tid], v.y);
        } else {
            pRow[(size_t)c * N_ROWS + I * TILE + tid] = v;        // owner-unique slot
        }
    }
}

// ---------------------------------------------------------------- reduce+loss+mean
// Valid slots: row r (tile it=r>>7): pRow[c][r] for c=it/4..31; pCol[I][r] for I=0..it-1.
template<bool ATOM>
__global__ __launch_bounds__(256) void k_reduce(const float2* __restrict__ pRow,
                                                const float2* __restrict__ pCol,
                                                float* __restrict__ accum) {
    int row = blockIdx.x * 256 + threadIdx.x;
    float num = 0.f, tot = 0.f;
    if (ATOM) {
        num = ((const float*)pRow)[row];
        tot = ((const float*)pCol)[row];
    } else {
        int it = row >> 7;
        for (int c = it >> 2; c < NCHUNK; ++c) {
            float2 v = pRow[(size_t)c * N_ROWS + row];
            num += v.x; tot += v.y;
        }
        for (int I = 0; I < it; ++I) {
            float2 v = pCol[(size_t)I * N_ROWS + row];
            num += v.x; tot += v.y;
        }
    }
    float ediag = expf(14.285714285714286f);       // exp(1/T), exact diagonal
    float denom = tot - num + ediag;
    float loss = -logf(num / denom + 1e-8f);
#pragma unroll
    for (int i = 1; i < 64; i <<= 1) loss += __shfl_xor(loss, i, 64);
    __shared__ float red[4];
    if ((threadIdx.x & 63) == 0) red[threadIdx.x >> 6] = loss;
    __syncthreads();
    if (threadIdx.x == 0)
        atomicAdd(accum, red[0] + red[1] + red[2] + red[3]);
}

__global__ void k_final(const float* __restrict__ accum, float* __restrict__ out) {
    out[0] = accum[0] / (float)N_ROWS;
}

// ---------------------------------------------------------------- launcher
extern "C" void kernel_launch(void* const* d_in, const int* in_sizes, int n_in,
                              void* d_out, int out_size, void* d_ws, size_t ws_size,
                              hipStream_t stream) {
    const float* F  = (const float*)d_in[0];
    const int* lab  = (const int*)d_in[1];
    float* out      = (float*)d_out;
    char* ws        = (char*)d_ws;

    __hip_bfloat16* G = (__hip_bfloat16*)ws;                         // 4 MB
    float* accum = (float*)(ws + ((size_t)4 << 20));                 // 16 B
    char* base   = ws + ((size_t)4 << 20) + 1024;
    float2* pRow = (float2*)base;                                    // 4 MB  [32][16384]
    float2* pCol = (float2*)(base + ((size_t)4 << 20));              // 16 MB [128][16384]

    k_normalize<<<N_ROWS / 4, 256, 0, stream>>>(F, G);
    hipMemsetAsync(accum, 0, 16, stream);

    size_t need = ((size_t)4 << 20) + 1024 + ((size_t)4 << 20) + ((size_t)16 << 20);
    int nblocks = 2112;   // sum over I-tiles of #4-wide J-chunks (triangle)
    if (ws_size >= need) {
        k_tiles<false><<<nblocks, 256, 0, stream>>>(G, lab, pRow, pCol);
        k_reduce<false><<<N_ROWS / 256, 256, 0, stream>>>(pRow, pCol, accum);
    } else {
        // fallback: pRow/pCol reused as rN[N]/rT[N] float accumulators
        hipMemsetAsync(pRow, 0, (size_t)N_ROWS * sizeof(float), stream);
        hipMemsetAsync(pCol, 0, (size_t)N_ROWS * sizeof(float), stream);
        k_tiles<true><<<nblocks, 256, 0, stream>>>(G, lab, pRow, pCol);
        k_reduce<true><<<N_ROWS / 256, 256, 0, stream>>>(pRow, pCol, accum);
    }
    k_final<<<1, 1, 0, stream>>>(accum, out);
}

// Round 15
// 229.644 us; speedup vs baseline: 1.0826x; 1.0218x over previous
//
#include <hip/hip_runtime.h>
#include <hip/hip_bf16.h>
#include <cstdint>
#include <cstddef>

// SupConLoss, N=16384 D=128, T=0.07, 100 classes.
// Round 6: Round-5 single-phase structure + col-combine RACE FIX.
// Round-5 bug: both wr-waves of a column strip stored the same pCol slot
// with only their own 64-row half (intra-wave shuffle reduce doesn't cross
// waves). Fix: batched end-phase combine via LDS (wr=0 deposits, wr=1
// combines+stores) -- 2 extra barriers per BLOCK, main loop still one
// barrier per tile.

#define N_ROWS 16384
#define DIM    128
#define TILE   128
#define NTILES (N_ROWS / TILE)   // 128
#define NCHUNK 32                // J-chunks of 4 tiles

// exp(sim/T) = exp2( dot * log2(e)/T ); bake sqrt(log2(e)/T) into features.
#define FEAT_SCALE 4.5398164f

typedef __attribute__((ext_vector_type(8))) short bf16x8;
typedef __attribute__((ext_vector_type(4))) float f32x4;

typedef const __attribute__((address_space(1))) unsigned int* gas_ptr;
typedef __attribute__((address_space(3))) unsigned int* las_ptr;

// ---------------------------------------------------------------- normalize
__global__ __launch_bounds__(256) void k_normalize(const float* __restrict__ F,
                                                   __hip_bfloat16* __restrict__ G) {
    int tid  = threadIdx.x;
    int lane = tid & 63;
    int wave = tid >> 6;
    int row  = blockIdx.x * 4 + wave;
    const float2* src = (const float2*)(F + (size_t)row * DIM) + lane;
    float2 x = *src;
    float s = x.x * x.x + x.y * x.y;
#pragma unroll
    for (int i = 1; i < 64; i <<= 1) s += __shfl_xor(s, i, 64);
    float scale = FEAT_SCALE / fmaxf(sqrtf(s), 1e-12f);
    __hip_bfloat162 h;
    h.x = __float2bfloat16(x.x * scale);
    h.y = __float2bfloat16(x.y * scale);
    ((__hip_bfloat162*)(G + (size_t)row * DIM))[lane] = h;
}

// ---------------------------------------------------------------- main tiles
template<bool ATOM>
__global__ __launch_bounds__(256) void k_tiles(const __hip_bfloat16* __restrict__ G,
                                               const int* __restrict__ lab,
                                               float2* __restrict__ pRow,
                                               float2* __restrict__ pCol) {
    __shared__ __align__(16) char lds[65536 + 4096];
    float* sCol = (float*)(lds + 65536);   // 1024 floats: col combine
    float* sRed = (float*)(lds + 65536);   // 512 floats: row phase (after barrier)

    int tid = threadIdx.x;

    // ---- triangular decode: bid -> (I, chunk c) with c >= I/4
    int bid = blockIdx.x;
    int u = bid >> 2, i2 = bid & 3;
    int c = (int)((sqrtf(8.f * (float)u + 1.f) - 1.f) * 0.5f);
    while ((c + 1) * (c + 2) / 2 <= u) ++c;
    while (c * (c + 1) / 2 > u) --c;
    int g = u - c * (c + 1) / 2;          // g <= c
    int I = g * 4 + i2;
    int J0 = (I > c * 4) ? I : c * 4;
    int nj = c * 4 + 4 - J0;              // 1..4

    // ---- stage A -> half0, B(J0) -> half1  (pre-swizzled source)
    const char* gbase = (const char*)G;
    {
        const char* gA = gbase + (size_t)I * (TILE * DIM * 2);
        const char* gB = gbase + (size_t)J0 * (TILE * DIM * 2);
#pragma unroll
        for (int p = 0; p < 8; ++p) {
            int o = p * 4096 + tid * 16;
            int so = o ^ (((o >> 8) & 7) << 4);
            __builtin_amdgcn_global_load_lds((gas_ptr)(gA + so), (las_ptr)(lds + o), 16, 0, 0);
            __builtin_amdgcn_global_load_lds((gas_ptr)(gB + so), (las_ptr)(lds + 32768 + o), 16, 0, 0);
        }
    }

    int lane = tid & 63, w = tid >> 6;
    int wr = w >> 1, wc = w & 1;          // 2x2 waves of 64x64
    int lr = lane & 15, lhi = lane >> 4;

    __syncthreads();                      // A,B0 resident

    // ---- A fragments to registers, row labels
    bf16x8 afr[4][4];                     // [m][kk]
#pragma unroll
    for (int m = 0; m < 4; ++m) {
        int row = wr * 64 + m * 16 + lr;
#pragma unroll
        for (int kk = 0; kk < 4; ++kk) {
            int lin = row * 256 + kk * 64 + lhi * 16;
            afr[m][kk] = *(const bf16x8*)(lds + (lin ^ ((row & 7) << 4)));
        }
    }
    int rowbase = I * TILE + wr * 64;
    int colwave = wc * 64;                // this wave's col offset within tile
    int labr[4][4];
#pragma unroll
    for (int m = 0; m < 4; ++m)
#pragma unroll
        for (int r = 0; r < 4; ++r) labr[m][r] = lab[rowbase + m * 16 + lhi * 4 + r];

    float rn[4][4], rt[4][4];             // row partials (accumulate all tiles)
    float cnA[4][4], ctA[4][4];           // col partials per tile t (static idx)
#pragma unroll
    for (int m = 0; m < 4; ++m)
#pragma unroll
        for (int r = 0; r < 4; ++r) { rn[m][r] = 0.f; rt[m][r] = 0.f; }
#pragma unroll
    for (int t = 0; t < 4; ++t)
#pragma unroll
        for (int n = 0; n < 4; ++n) { cnA[t][n] = 0.f; ctA[t][n] = 0.f; }

    __syncthreads();                      // all waves done reading A half

    // ---- J loop: fully unrolled, ONE barrier per tile
#pragma unroll
    for (int t = 0; t < 4; ++t) {
        if (t < nj) {
            char* buf = lds + (((t & 1) ^ 1) << 15);   // B(t)
            int Jt = J0 + t;

            if (t + 1 < nj) {             // stage B(t+1) into the other half
                const char* gB = gbase + (size_t)(Jt + 1) * (TILE * DIM * 2);
                char* nbuf = lds + ((t & 1) << 15);
#pragma unroll
                for (int p = 0; p < 8; ++p) {
                    int o = p * 4096 + tid * 16;
                    int so = o ^ (((o >> 8) & 7) << 4);
                    __builtin_amdgcn_global_load_lds((gas_ptr)(gB + so), (las_ptr)(nbuf + o), 16, 0, 0);
                }
            }
            __builtin_amdgcn_sched_barrier(0);  // keep stage issue first

            int colbase = Jt * TILE + colwave;
            int labc[4];
#pragma unroll
            for (int n = 0; n < 4; ++n) labc[n] = lab[colbase + n * 16 + lr];

            f32x4 acc[4][4];
#pragma unroll
            for (int m = 0; m < 4; ++m)
#pragma unroll
                for (int n = 0; n < 4; ++n) acc[m][n] = (f32x4){0.f, 0.f, 0.f, 0.f};

#pragma unroll
            for (int kk = 0; kk < 4; ++kk) {
#pragma unroll
                for (int n = 0; n < 4; ++n) {
                    int row = colwave + n * 16 + lr;
                    int lin = row * 256 + kk * 64 + lhi * 16;
                    bf16x8 b = *(const bf16x8*)(buf + (lin ^ ((row & 7) << 4)));
#pragma unroll
                    for (int m = 0; m < 4; ++m)
                        acc[m][n] = __builtin_amdgcn_mfma_f32_16x16x32_bf16(afr[m][kk], b, acc[m][n], 0, 0, 0);
                }
            }

            // ---- uniform epilogue: no diag test (corrected below)
#pragma unroll
            for (int n = 0; n < 4; ++n) {
#pragma unroll
                for (int m = 0; m < 4; ++m) {
#pragma unroll
                    for (int r = 0; r < 4; ++r) {
                        float e = __builtin_amdgcn_exp2f(acc[m][n][r]);
                        float me = (labr[m][r] == labc[n]) ? e : 0.f;
                        rn[m][r] += me;  rt[m][r] += e;
                        cnA[t][n] += me; ctA[t][n] += e;
                    }
                }
            }

            // ---- diagonal post-correction (uniform branch, static indices)
            if (Jt == I) {
#pragma unroll
                for (int m = 0; m < 4; ++m)
#pragma unroll
                    for (int r = 0; r < 4; ++r) {
                        bool d = (wr == wc) && (lhi * 4 + r == lr);
                        float e = __builtin_amdgcn_exp2f(acc[m][m][r]);
                        e = d ? e : 0.f;
                        rn[m][r] -= e;  rt[m][r] -= e;
                        cnA[t][m] -= e; ctA[t][m] -= e;
                    }
            }

            __syncthreads();              // B(t) consumed; B(t+1) resident
        }
    }

    // ---- col partials end-phase (race-free): wr=0 deposits, wr=1 combines.
    if (wr == 0) {
#pragma unroll
        for (int t = 0; t < 4; ++t)
#pragma unroll
            for (int n = 0; n < 4; ++n) {
                float v1 = cnA[t][n], v2 = ctA[t][n];
                v1 += __shfl_xor(v1, 16, 64); v1 += __shfl_xor(v1, 32, 64);
                v2 += __shfl_xor(v2, 16, 64); v2 += __shfl_xor(v2, 32, 64);
                if (lhi == 0) {
                    int idx = ((wc * 4 + t) * 4 + n) * 16 + lr;
                    sCol[idx]       = v1;
                    sCol[512 + idx] = v2;
                }
            }
    }
    __syncthreads();
    if (wr == 1) {
#pragma unroll
        for (int t = 0; t < 4; ++t) {
            if (t < nj) {
                int Jt = J0 + t;
                if (Jt != I) {
#pragma unroll
                    for (int n = 0; n < 4; ++n) {
                        float v1 = cnA[t][n], v2 = ctA[t][n];
                        v1 += __shfl_xor(v1, 16, 64); v1 += __shfl_xor(v1, 32, 64);
                        v2 += __shfl_xor(v2, 16, 64); v2 += __shfl_xor(v2, 32, 64);
                        if (lhi == 0) {
                            int idx = ((wc * 4 + t) * 4 + n) * 16 + lr;
                            v1 += sCol[idx];
                            v2 += sCol[512 + idx];
                            int col = colwave + n * 16 + lr;
                            if (ATOM) {
                                float* rNd = (float*)pRow;  float* rTd = (float*)pCol;
                                atomicAdd(&rNd[Jt * TILE + col], v1);
                                atomicAdd(&rTd[Jt * TILE + col], v2);
                            } else {
                                float2 v; v.x = v1; v.y = v2;
                                pCol[(size_t)I * N_ROWS + Jt * TILE + col] = v;
                            }
                        }
                    }
                }
            }
        }
    }
    __syncthreads();                      // sCol region free for row phase

    // ---- row partials: reduce over lr once per block via LDS
#pragma unroll
    for (int m = 0; m < 4; ++m)
#pragma unroll
        for (int r = 0; r < 4; ++r) {
            float v1 = rn[m][r], v2 = rt[m][r];
#pragma unroll
            for (int s = 1; s < 16; s <<= 1) {
                v1 += __shfl_xor(v1, s, 64);
                v2 += __shfl_xor(v2, s, 64);
            }
            if (lr == 0) {
                int rowt = wr * 64 + m * 16 + lhi * 4 + r;
                sRed[wc * 128 + rowt]       = v1;
                sRed[256 + wc * 128 + rowt] = v2;
            }
        }
    __syncthreads();
    if (tid < 128) {
        float2 v;
        v.x = sRed[tid] + sRed[128 + tid];
        v.y = sRed[256 + tid] + sRed[384 + tid];
        if (ATOM) {
            float* rNd = (float*)pRow;  float* rTd = (float*)pCol;
            atomicAdd(&rNd[I * TILE + tid], v.x);
            atomicAdd(&rTd[I * TILE + tid], v.y);
        } else {
            pRow[(size_t)c * N_ROWS + I * TILE + tid] = v;
        }
    }
}

// ---------------------------------------------------------------- reduce+loss+mean
// Valid slots: row r (tile it=r>>7): pRow[c][r] for c=it/4..31; pCol[I][r] for I=0..it-1.
template<bool ATOM>
__global__ __launch_bounds__(256) void k_reduce(const float2* __restrict__ pRow,
                                                const float2* __restrict__ pCol,
                                                float* __restrict__ accum) {
    int row = blockIdx.x * 256 + threadIdx.x;
    float num = 0.f, tot = 0.f;
    if (ATOM) {
        num = ((const float*)pRow)[row];
        tot = ((const float*)pCol)[row];
    } else {
        int it = row >> 7;
        for (int c = it >> 2; c < NCHUNK; ++c) {
            float2 v = pRow[(size_t)c * N_ROWS + row];
            num += v.x; tot += v.y;
        }
        for (int I = 0; I < it; ++I) {
            float2 v = pCol[(size_t)I * N_ROWS + row];
            num += v.x; tot += v.y;
        }
    }
    float ediag = expf(14.285714285714286f);       // exp(1/T), exact diagonal
    float denom = tot - num + ediag;
    float loss = -logf(num / denom + 1e-8f);
#pragma unroll
    for (int i = 1; i < 64; i <<= 1) loss += __shfl_xor(loss, i, 64);
    __shared__ float red[4];
    if ((threadIdx.x & 63) == 0) red[threadIdx.x >> 6] = loss;
    __syncthreads();
    if (threadIdx.x == 0)
        atomicAdd(accum, red[0] + red[1] + red[2] + red[3]);
}

__global__ void k_final(const float* __restrict__ accum, float* __restrict__ out) {
    out[0] = accum[0] / (float)N_ROWS;
}

// ---------------------------------------------------------------- launcher
extern "C" void kernel_launch(void* const* d_in, const int* in_sizes, int n_in,
                              void* d_out, int out_size, void* d_ws, size_t ws_size,
                              hipStream_t stream) {
    const float* F  = (const float*)d_in[0];
    const int* lab  = (const int*)d_in[1];
    float* out      = (float*)d_out;
    char* ws        = (char*)d_ws;

    __hip_bfloat16* G = (__hip_bfloat16*)ws;                         // 4 MB
    float* accum = (float*)(ws + ((size_t)4 << 20));                 // 16 B
    char* base   = ws + ((size_t)4 << 20) + 1024;
    float2* pRow = (float2*)base;                                    // 4 MB  [32][16384]
    float2* pCol = (float2*)(base + ((size_t)4 << 20));              // 16 MB [128][16384]

    k_normalize<<<N_ROWS / 4, 256, 0, stream>>>(F, G);
    hipMemsetAsync(accum, 0, 16, stream);

    size_t need = ((size_t)4 << 20) + 1024 + ((size_t)4 << 20) + ((size_t)16 << 20);
    int nblocks = 2112;   // triangular chunk grid
    if (ws_size >= need) {
        k_tiles<false><<<nblocks, 256, 0, stream>>>(G, lab, pRow, pCol);
        k_reduce<false><<<N_ROWS / 256, 256, 0, stream>>>(pRow, pCol, accum);
    } else {
        hipMemsetAsync(pRow, 0, (size_t)N_ROWS * sizeof(float), stream);
        hipMemsetAsync(pCol, 0, (size_t)N_ROWS * sizeof(float), stream);
        k_tiles<true><<<nblocks, 256, 0, stream>>>(G, lab, pRow, pCol);
        k_reduce<true><<<N_ROWS / 256, 256, 0, stream>>>(pRow, pCol, accum);
    }
    k_final<<<1, 1, 0, stream>>>(accum, out);
}